// Round 1
// baseline (879.371 us; speedup 1.0000x reference)
//
#include <hip/hip_runtime.h>
#include <math.h>

// Problem constants (B,N,C,H,D) = (8,1024,512,8,64)
constexpr int kB = 8, kS = 1024, kC = 512, kH = 8, kD = 64;

// ---------------------------------------------------------------------------
// QKV GEMM: C[m,n] = sum_k x[m,k] * qkv_w[n,k] + qkv_b[n]   (NT gemm)
// M=8192, N=1536, K=512. Tile 128x128, BK=16, 256 thr, 8x8 per thread.
// Fused: q/k head-LayerNorm (D=64) in epilogue, scatter to q/k/v [bh][n][d].
// ---------------------------------------------------------------------------
__global__ __launch_bounds__(256) void qkv_kernel(
    const float* __restrict__ x, const float* __restrict__ w, const float* __restrict__ bias,
    const float* __restrict__ qn_w, const float* __restrict__ qn_b,
    const float* __restrict__ kn_w, const float* __restrict__ kn_b,
    float* __restrict__ qb, float* __restrict__ kb, float* __restrict__ vb)
{
    __shared__ float As[16][132];   // [k][m-row], +4 pad keeps stores 2-way max
    __shared__ float Bs[16][132];   // [k][n-row]
    const int tid = threadIdx.x;
    const int tx = tid & 15, ty = tid >> 4;
    const int n0 = blockIdx.x * 128, m0 = blockIdx.y * 128;

    float acc[8][8];
#pragma unroll
    for (int i = 0; i < 8; ++i)
#pragma unroll
        for (int j = 0; j < 8; ++j) acc[i][j] = 0.f;

    for (int k0 = 0; k0 < kC; k0 += 16) {
        __syncthreads();
#pragma unroll
        for (int l = 0; l < 2; ++l) {
            const int i = tid + l * 256;
            const int r = i >> 2, q4 = i & 3;
            const float4 av = *(const float4*)(x + (m0 + r) * kC + k0 + q4 * 4);
            const float4 bv = *(const float4*)(w + (n0 + r) * kC + k0 + q4 * 4);
            As[q4 * 4 + 0][r] = av.x; As[q4 * 4 + 1][r] = av.y;
            As[q4 * 4 + 2][r] = av.z; As[q4 * 4 + 3][r] = av.w;
            Bs[q4 * 4 + 0][r] = bv.x; Bs[q4 * 4 + 1][r] = bv.y;
            Bs[q4 * 4 + 2][r] = bv.z; Bs[q4 * 4 + 3][r] = bv.w;
        }
        __syncthreads();
#pragma unroll
        for (int kk = 0; kk < 16; ++kk) {
            const float4 a0 = *(const float4*)&As[kk][ty * 4];
            const float4 a1 = *(const float4*)&As[kk][ty * 4 + 64];
            const float4 b0 = *(const float4*)&Bs[kk][tx * 4];
            const float4 b1 = *(const float4*)&Bs[kk][tx * 4 + 64];
            const float ar[8] = {a0.x, a0.y, a0.z, a0.w, a1.x, a1.y, a1.z, a1.w};
            const float br[8] = {b0.x, b0.y, b0.z, b0.w, b1.x, b1.y, b1.z, b1.w};
#pragma unroll
            for (int i = 0; i < 8; ++i)
#pragma unroll
                for (int j = 0; j < 8; ++j)
                    acc[i][j] = fmaf(ar[i], br[j], acc[i][j]);
        }
    }

    // ---- epilogue: bias, (q/k) LayerNorm over D=64, scatter to [b,h,n,d] ----
    const int t = blockIdx.x >> 2;      // 4 n-tiles each of q,k,v (uniform per block)
    const int d0 = tx * 4;              // d within head for this thread's columns
    float lwv[4] = {1.f, 1.f, 1.f, 1.f}, lbv[4] = {0.f, 0.f, 0.f, 0.f};
    if (t == 0) {
#pragma unroll
        for (int j = 0; j < 4; ++j) { lwv[j] = qn_w[d0 + j]; lbv[j] = qn_b[d0 + j]; }
    } else if (t == 1) {
#pragma unroll
        for (int j = 0; j < 4; ++j) { lwv[j] = kn_w[d0 + j]; lbv[j] = kn_b[d0 + j]; }
    }
    float* const outp = (t == 0) ? qb : (t == 1) ? kb : vb;
    const int h_lo = (n0 >> 6) & 7;     // tile covers exactly 2 heads
    const int h_hi = h_lo + 1;
    float blo[4], bhi[4];
#pragma unroll
    for (int j = 0; j < 4; ++j) {
        blo[j] = bias[n0 + d0 + j];
        bhi[j] = bias[n0 + 64 + d0 + j];
    }
#pragma unroll
    for (int i = 0; i < 8; ++i) {
        const int row = m0 + ty * 4 + (i < 4 ? i : 60 + i);
        const int b = row >> 10, np = row & 1023;
#pragma unroll
        for (int half = 0; half < 2; ++half) {
            float v0 = acc[i][half * 4 + 0] + (half ? bhi[0] : blo[0]);
            float v1 = acc[i][half * 4 + 1] + (half ? bhi[1] : blo[1]);
            float v2 = acc[i][half * 4 + 2] + (half ? bhi[2] : blo[2]);
            float v3 = acc[i][half * 4 + 3] + (half ? bhi[3] : blo[3]);
            if (t < 2) {
                // row of 64 spread over 16 lanes (same ty group) x 4 values
                float s  = v0 + v1 + v2 + v3;
                float sq = v0 * v0 + v1 * v1 + v2 * v2 + v3 * v3;
#pragma unroll
                for (int off = 1; off < 16; off <<= 1) {
                    s  += __shfl_xor(s, off);
                    sq += __shfl_xor(sq, off);
                }
                const float mu  = s * (1.f / 64.f);
                const float var = sq * (1.f / 64.f) - mu * mu;   // biased var (jnp.var)
                const float rs  = rsqrtf(var + 1e-5f);
                v0 = (v0 - mu) * rs * lwv[0] + lbv[0];
                v1 = (v1 - mu) * rs * lwv[1] + lbv[1];
                v2 = (v2 - mu) * rs * lwv[2] + lbv[2];
                v3 = (v3 - mu) * rs * lwv[3] + lbv[3];
            }
            const int h = half ? h_hi : h_lo;
            float4 o; o.x = v0; o.y = v1; o.z = v2; o.w = v3;
            *(float4*)(outp + ((b * kH + h) * kS + np) * kD + d0) = o;
        }
    }
}

// ---------------------------------------------------------------------------
// Gate: gate[bh][n] = sigmoid( sum_d x[b,n,h*64+d]*gate_w[h,d] + gate_b[h] )
// One wave per (bh,n); lane = d; coalesced 256B read; 6-step shuffle reduce.
// ---------------------------------------------------------------------------
__global__ __launch_bounds__(256) void gate_kernel(
    const float* __restrict__ x, const float* __restrict__ gw,
    const float* __restrict__ gb, float* __restrict__ gate)
{
    const int wid  = (blockIdx.x * 256 + threadIdx.x) >> 6;
    const int lane = threadIdx.x & 63;
    const int bh = wid >> 10, n = wid & 1023;
    const int b = bh >> 3, h = bh & 7;
    float a = x[(b * kS + n) * kC + h * kD + lane] * gw[h * kD + lane];
#pragma unroll
    for (int off = 32; off > 0; off >>= 1) a += __shfl_xor(a, off);
    if (lane == 0) {
        const float al = a + gb[h];
        gate[bh * kS + n] = 1.0f / (1.0f + __expf(-al));
    }
}

// ---------------------------------------------------------------------------
// Flash attention fp32. Block = (head bh, 32 q-rows). 4 waves x 8 rows.
// QK^T: lane = key (64-key tile in 64 VGPRs), Q broadcast from LDS.
// PV:   lane = d, P transposed through LDS, V scalar reads (f4 XOR swizzle).
// Writes ctx IN-PLACE over q (each block reads only its own q rows, prologue-only).
// ---------------------------------------------------------------------------
__global__ __launch_bounds__(256) void attn_kernel(
    const float* qp_base,            // q  [bh][n][d]  (NOT restrict: aliases ctx)
    const float* __restrict__ kb, const float* __restrict__ vb,
    const float* __restrict__ gate,
    float* ctx)                      // aliases qp_base
{
    __shared__ float4 Kt[64 * 16];   // [key][d4 ^ (key&15)]  16B-aligned, swizzled
    __shared__ float4 Vt[64 * 16];
    __shared__ float4 Qs[32 * 16];   // [row][d4]  broadcast-read only
    __shared__ float  Pl[32][68];    // P transposed; stride 68 keeps f4 align
    const int tid  = threadIdx.x;
    const int lane = tid & 63;
    const int w8   = (tid >> 6) * 8;            // this wave's first row
    const int bh   = blockIdx.x >> 5;
    const int r0   = (blockIdx.x & 31) * 32;
    const float* qp = qp_base + (bh * kS + r0) * kD;
    const float* kp = kb + bh * kS * kD;
    const float* vp = vb + bh * kS * kD;

    // Q tile (pre-scaled by D^-0.5) -> LDS
#pragma unroll
    for (int l = 0; l < 2; ++l) {
        const int i = tid + l * 256;
        const int r = i >> 4, c = i & 15;
        float4 v = *(const float4*)(qp + r * 64 + c * 4);
        v.x *= 0.125f; v.y *= 0.125f; v.z *= 0.125f; v.w *= 0.125f;
        Qs[r * 16 + c] = v;
    }

    float m_run[8], l_run[8], acc[8], s[8];
#pragma unroll
    for (int r = 0; r < 8; ++r) { m_run[r] = -1e30f; l_run[r] = 0.f; acc[r] = 0.f; }

    for (int kt = 0; kt < 16; ++kt) {
        __syncthreads();
#pragma unroll
        for (int l = 0; l < 4; ++l) {
            const int i = tid + l * 256;
            const int r = i >> 4, c = i & 15;
            const int sw = c ^ (r & 15);
            Kt[r * 16 + sw] = *(const float4*)(kp + kt * 4096 + r * 64 + c * 4);
            Vt[r * 16 + sw] = *(const float4*)(vp + kt * 4096 + r * 64 + c * 4);
        }
        __syncthreads();

        // ---- scores: lane = key ----
        float4 kr[16];
#pragma unroll
        for (int c = 0; c < 16; ++c) kr[c] = Kt[lane * 16 + (c ^ (lane & 15))];
#pragma unroll
        for (int r = 0; r < 8; ++r) {
            float a0 = 0.f, a1 = 0.f, a2 = 0.f, a3 = 0.f;
#pragma unroll
            for (int c = 0; c < 16; ++c) {
                const float4 q = Qs[(w8 + r) * 16 + c];   // broadcast read
                a0 = fmaf(q.x, kr[c].x, a0);
                a1 = fmaf(q.y, kr[c].y, a1);
                a2 = fmaf(q.z, kr[c].z, a2);
                a3 = fmaf(q.w, kr[c].w, a3);
            }
            s[r] = (a0 + a1) + (a2 + a3);
        }

        // ---- online softmax ----
#pragma unroll
        for (int r = 0; r < 8; ++r) {
            float mt = s[r];
#pragma unroll
            for (int off = 32; off > 0; off >>= 1) mt = fmaxf(mt, __shfl_xor(mt, off));
            const float mn = fmaxf(m_run[r], mt);
            const float p  = __expf(s[r] - mn);
            float ps = p;
#pragma unroll
            for (int off = 32; off > 0; off >>= 1) ps += __shfl_xor(ps, off);
            const float corr = __expf(m_run[r] - mn);
            l_run[r] = l_run[r] * corr + ps;
            acc[r]  *= corr;
            m_run[r] = mn;
            Pl[w8 + r][lane] = p;
        }
        __syncthreads();   // P visible (also orders LDS within wave)

        // ---- PV: lane = d ----
        const float* VtF = (const float*)Vt;
        const int dl = lane >> 2, dm = lane & 3;
#pragma unroll 4
        for (int j4 = 0; j4 < 16; ++j4) {
            const int j0 = j4 * 4;
            const float v0 = VtF[(j0 + 0) * 64 + ((dl ^ ((j0 + 0) & 15)) << 2) + dm];
            const float v1 = VtF[(j0 + 1) * 64 + ((dl ^ ((j0 + 1) & 15)) << 2) + dm];
            const float v2 = VtF[(j0 + 2) * 64 + ((dl ^ ((j0 + 2) & 15)) << 2) + dm];
            const float v3 = VtF[(j0 + 3) * 64 + ((dl ^ ((j0 + 3) & 15)) << 2) + dm];
#pragma unroll
            for (int r = 0; r < 8; ++r) {
                const float4 p4 = *(const float4*)&Pl[w8 + r][j0];   // broadcast
                acc[r] = fmaf(p4.x, v0, acc[r]);
                acc[r] = fmaf(p4.y, v1, acc[r]);
                acc[r] = fmaf(p4.z, v2, acc[r]);
                acc[r] = fmaf(p4.w, v3, acc[r]);
            }
        }
    }

    // ---- epilogue: 1/l, gate, store ctx (in-place over q) ----
#pragma unroll
    for (int r = 0; r < 8; ++r) {
        const int row = r0 + w8 + r;
        const float g = gate[bh * kS + row];
        const float o = acc[r] * (g / l_run[r]);
        ctx[(bh * kS + row) * kD + lane] = o;
    }
}

// ---------------------------------------------------------------------------
// Output projection: out[m,n] = sum_k ctx_perm[m,k] * proj_w[n,k] + proj_b[n]
// ctx_perm[m,k] = ctx[bh][np][d] with b=m>>10, np=m&1023, h=k>>6, d=k&63.
// ---------------------------------------------------------------------------
__global__ __launch_bounds__(256) void proj_kernel(
    const float* __restrict__ ctx, const float* __restrict__ w,
    const float* __restrict__ bias, float* __restrict__ out)
{
    __shared__ float As[16][132];
    __shared__ float Bs[16][132];
    const int tid = threadIdx.x;
    const int tx = tid & 15, ty = tid >> 4;
    const int n0 = blockIdx.x * 128, m0 = blockIdx.y * 128;
    const int b = m0 >> 10;   // whole tile within one batch image

    float acc[8][8];
#pragma unroll
    for (int i = 0; i < 8; ++i)
#pragma unroll
        for (int j = 0; j < 8; ++j) acc[i][j] = 0.f;

    for (int k0 = 0; k0 < kC; k0 += 16) {
        __syncthreads();
#pragma unroll
        for (int l = 0; l < 2; ++l) {
            const int i = tid + l * 256;
            const int r = i >> 2, q4 = i & 3;
            const int np = (m0 + r) & 1023;
            const int k = k0 + q4 * 4;
            const int h = k >> 6, d = k & 63;
            const float4 av = *(const float4*)(ctx + ((b * kH + h) * kS + np) * kD + d);
            const float4 bv = *(const float4*)(w + (n0 + r) * kC + k);
            As[q4 * 4 + 0][r] = av.x; As[q4 * 4 + 1][r] = av.y;
            As[q4 * 4 + 2][r] = av.z; As[q4 * 4 + 3][r] = av.w;
            Bs[q4 * 4 + 0][r] = bv.x; Bs[q4 * 4 + 1][r] = bv.y;
            Bs[q4 * 4 + 2][r] = bv.z; Bs[q4 * 4 + 3][r] = bv.w;
        }
        __syncthreads();
#pragma unroll
        for (int kk = 0; kk < 16; ++kk) {
            const float4 a0 = *(const float4*)&As[kk][ty * 4];
            const float4 a1 = *(const float4*)&As[kk][ty * 4 + 64];
            const float4 b0 = *(const float4*)&Bs[kk][tx * 4];
            const float4 b1 = *(const float4*)&Bs[kk][tx * 4 + 64];
            const float ar[8] = {a0.x, a0.y, a0.z, a0.w, a1.x, a1.y, a1.z, a1.w};
            const float br[8] = {b0.x, b0.y, b0.z, b0.w, b1.x, b1.y, b1.z, b1.w};
#pragma unroll
            for (int i = 0; i < 8; ++i)
#pragma unroll
                for (int j = 0; j < 8; ++j)
                    acc[i][j] = fmaf(ar[i], br[j], acc[i][j]);
        }
    }

    const int d0 = tx * 4;
    float blo[4], bhi[4];
#pragma unroll
    for (int j = 0; j < 4; ++j) {
        blo[j] = bias[n0 + d0 + j];
        bhi[j] = bias[n0 + 64 + d0 + j];
    }
#pragma unroll
    for (int i = 0; i < 8; ++i) {
        const int row = m0 + ty * 4 + (i < 4 ? i : 60 + i);
#pragma unroll
        for (int half = 0; half < 2; ++half) {
            float4 o;
            o.x = acc[i][half * 4 + 0] + (half ? bhi[0] : blo[0]);
            o.y = acc[i][half * 4 + 1] + (half ? bhi[1] : blo[1]);
            o.z = acc[i][half * 4 + 2] + (half ? bhi[2] : blo[2]);
            o.w = acc[i][half * 4 + 3] + (half ? bhi[3] : blo[3]);
            *(float4*)(out + row * kC + n0 + half * 64 + d0) = o;
        }
    }
}

// ---------------------------------------------------------------------------
extern "C" void kernel_launch(void* const* d_in, const int* in_sizes, int n_in,
                              void* d_out, int out_size, void* d_ws, size_t ws_size,
                              hipStream_t stream)
{
    const float* x      = (const float*)d_in[0];
    const float* qkv_w  = (const float*)d_in[1];
    const float* qkv_b  = (const float*)d_in[2];
    const float* qn_w   = (const float*)d_in[3];
    const float* qn_b   = (const float*)d_in[4];
    const float* kn_w   = (const float*)d_in[5];
    const float* kn_b   = (const float*)d_in[6];
    const float* gate_w = (const float*)d_in[7];
    const float* gate_b = (const float*)d_in[8];
    const float* proj_w = (const float*)d_in[9];
    const float* proj_b = (const float*)d_in[10];
    float* out = (float*)d_out;

    // workspace: q | k | v | gate   (ctx is written in-place over q)
    float* ws = (float*)d_ws;
    const size_t n1 = (size_t)kB * kH * kS * kD;   // 4,194,304 floats each
    float* qb   = ws;
    float* kbuf = ws + n1;
    float* vbuf = ws + 2 * n1;
    float* gate = ws + 3 * n1;                      // 65,536 floats
    // total ws use: 3*16 MB + 256 KB ≈ 48.25 MB

    qkv_kernel<<<dim3(12, 64), 256, 0, stream>>>(x, qkv_w, qkv_b, qn_w, qn_b,
                                                 kn_w, kn_b, qb, kbuf, vbuf);
    gate_kernel<<<dim3(16384), 256, 0, stream>>>(x, gate_w, gate_b, gate);
    attn_kernel<<<dim3(2048), 256, 0, stream>>>(qb, kbuf, vbuf, gate, qb);
    proj_kernel<<<dim3(4, 64), 256, 0, stream>>>(qb, proj_w, proj_b, out);
}

// Round 2
// 383.141 us; speedup vs baseline: 2.2952x; 2.2952x over previous
//
#include <hip/hip_runtime.h>
#include <math.h>

// Problem constants (B,N,C,H,D) = (8,1024,512,8,64)
constexpr int kB = 8, kS = 1024, kC = 512, kH = 8, kD = 64;

typedef _Float16 half8 __attribute__((ext_vector_type(8)));
typedef _Float16 half4v __attribute__((ext_vector_type(4)));
typedef float f32x4 __attribute__((ext_vector_type(4)));

// ---------------------------------------------------------------------------
// QKV GEMM: fp32 compute (no fp32 MFMA on CDNA4). Tile 128x128, BK=16.
// Epilogue: bias, q/k head-LayerNorm (D=64), q pre-scaled by D^-0.5,
// outputs stored as f16 [bh][n][d] for the MFMA attention kernel.
// ---------------------------------------------------------------------------
__global__ __launch_bounds__(256) void qkv_kernel(
    const float* __restrict__ x, const float* __restrict__ w, const float* __restrict__ bias,
    const float* __restrict__ qn_w, const float* __restrict__ qn_b,
    const float* __restrict__ kn_w, const float* __restrict__ kn_b,
    _Float16* __restrict__ qb, _Float16* __restrict__ kb, _Float16* __restrict__ vb)
{
    __shared__ float As[16][132];
    __shared__ float Bs[16][132];
    const int tid = threadIdx.x;
    const int tx = tid & 15, ty = tid >> 4;
    const int n0 = blockIdx.x * 128, m0 = blockIdx.y * 128;

    float acc[8][8];
#pragma unroll
    for (int i = 0; i < 8; ++i)
#pragma unroll
        for (int j = 0; j < 8; ++j) acc[i][j] = 0.f;

    for (int k0 = 0; k0 < kC; k0 += 16) {
        __syncthreads();
#pragma unroll
        for (int l = 0; l < 2; ++l) {
            const int i = tid + l * 256;
            const int r = i >> 2, q4 = i & 3;
            const float4 av = *(const float4*)(x + (m0 + r) * kC + k0 + q4 * 4);
            const float4 bv = *(const float4*)(w + (n0 + r) * kC + k0 + q4 * 4);
            As[q4 * 4 + 0][r] = av.x; As[q4 * 4 + 1][r] = av.y;
            As[q4 * 4 + 2][r] = av.z; As[q4 * 4 + 3][r] = av.w;
            Bs[q4 * 4 + 0][r] = bv.x; Bs[q4 * 4 + 1][r] = bv.y;
            Bs[q4 * 4 + 2][r] = bv.z; Bs[q4 * 4 + 3][r] = bv.w;
        }
        __syncthreads();
#pragma unroll
        for (int kk = 0; kk < 16; ++kk) {
            const float4 a0 = *(const float4*)&As[kk][ty * 4];
            const float4 a1 = *(const float4*)&As[kk][ty * 4 + 64];
            const float4 b0 = *(const float4*)&Bs[kk][tx * 4];
            const float4 b1 = *(const float4*)&Bs[kk][tx * 4 + 64];
            const float ar[8] = {a0.x, a0.y, a0.z, a0.w, a1.x, a1.y, a1.z, a1.w};
            const float br[8] = {b0.x, b0.y, b0.z, b0.w, b1.x, b1.y, b1.z, b1.w};
#pragma unroll
            for (int i = 0; i < 8; ++i)
#pragma unroll
                for (int j = 0; j < 8; ++j)
                    acc[i][j] = fmaf(ar[i], br[j], acc[i][j]);
        }
    }

    const int t = blockIdx.x >> 2;      // 0:q 1:k 2:v (uniform per block)
    const int d0 = tx * 4;
    float lwv[4] = {1.f, 1.f, 1.f, 1.f}, lbv[4] = {0.f, 0.f, 0.f, 0.f};
    if (t == 0) {
#pragma unroll
        for (int j = 0; j < 4; ++j) { lwv[j] = qn_w[d0 + j]; lbv[j] = qn_b[d0 + j]; }
    } else if (t == 1) {
#pragma unroll
        for (int j = 0; j < 4; ++j) { lwv[j] = kn_w[d0 + j]; lbv[j] = kn_b[d0 + j]; }
    }
    const float sc = (t == 0) ? 0.125f : 1.0f;   // q pre-scaled by D^-0.5
    _Float16* const outp = (t == 0) ? qb : (t == 1) ? kb : vb;
    const int h_lo = (n0 >> 6) & 7;
    const int h_hi = h_lo + 1;
    float blo[4], bhi[4];
#pragma unroll
    for (int j = 0; j < 4; ++j) {
        blo[j] = bias[n0 + d0 + j];
        bhi[j] = bias[n0 + 64 + d0 + j];
    }
#pragma unroll
    for (int i = 0; i < 8; ++i) {
        const int row = m0 + ty * 4 + (i < 4 ? i : 60 + i);
        const int b = row >> 10, np = row & 1023;
#pragma unroll
        for (int half = 0; half < 2; ++half) {
            float v0 = acc[i][half * 4 + 0] + (half ? bhi[0] : blo[0]);
            float v1 = acc[i][half * 4 + 1] + (half ? bhi[1] : blo[1]);
            float v2 = acc[i][half * 4 + 2] + (half ? bhi[2] : blo[2]);
            float v3 = acc[i][half * 4 + 3] + (half ? bhi[3] : blo[3]);
            if (t < 2) {
                float s  = v0 + v1 + v2 + v3;
                float sq = v0 * v0 + v1 * v1 + v2 * v2 + v3 * v3;
#pragma unroll
                for (int off = 1; off < 16; off <<= 1) {
                    s  += __shfl_xor(s, off);
                    sq += __shfl_xor(sq, off);
                }
                const float mu  = s * (1.f / 64.f);
                const float var = sq * (1.f / 64.f) - mu * mu;
                const float rs  = rsqrtf(var + 1e-5f);
                v0 = (v0 - mu) * rs * lwv[0] + lbv[0];
                v1 = (v1 - mu) * rs * lwv[1] + lbv[1];
                v2 = (v2 - mu) * rs * lwv[2] + lbv[2];
                v3 = (v3 - mu) * rs * lwv[3] + lbv[3];
            }
            const int h = half ? h_hi : h_lo;
            half4v o;
            o[0] = (_Float16)(v0 * sc); o[1] = (_Float16)(v1 * sc);
            o[2] = (_Float16)(v2 * sc); o[3] = (_Float16)(v3 * sc);
            *(half4v*)(outp + ((size_t)(b * kH + h) * kS + np) * kD + d0) = o;
        }
    }
}

// ---------------------------------------------------------------------------
// Gate: gate[bh][n] = sigmoid(dot(x[b,n,h*64:], gate_w[h]) + gate_b[h])
// ---------------------------------------------------------------------------
__global__ __launch_bounds__(256) void gate_kernel(
    const float* __restrict__ x, const float* __restrict__ gw,
    const float* __restrict__ gb, float* __restrict__ gate)
{
    const int wid  = (blockIdx.x * 256 + threadIdx.x) >> 6;
    const int lane = threadIdx.x & 63;
    const int bh = wid >> 10, n = wid & 1023;
    const int b = bh >> 3, h = bh & 7;
    float a = x[(b * kS + n) * kC + h * kD + lane] * gw[h * kD + lane];
#pragma unroll
    for (int off = 32; off > 0; off >>= 1) a += __shfl_xor(a, off);
    if (lane == 0) {
        const float al = a + gb[h];
        gate[bh * kS + n] = 1.0f / (1.0f + __expf(-al));
    }
}

// ---------------------------------------------------------------------------
// Flash attention, f16 MFMA (mfma_f32_16x16x32_f16, fp32 accum).
// Block = (head, 64 q-rows); 4 waves x 16 rows. KV tile = 64.
// LDS: K [kv][d] f16 (B-op of QK^T), V^T [d][kv] f16 (B-op of PV),
//      P [q][kv] f16 wave-private (A-op of PV). All rows 128B, XOR-swizzled:
//      chunk(bits 6:4) ^= (row ^ row>>3) & 7  -> bank-uniform b128 reads+writes.
// Writes ctx f32 [bh][n][d], gated.
// ---------------------------------------------------------------------------
__device__ __forceinline__ int swz(int row, int inner) {
    return row * 128 + (inner ^ ((((row >> 3) ^ row) & 7) << 4));
}

__global__ __launch_bounds__(256) void attn_kernel(
    const _Float16* __restrict__ qh, const _Float16* __restrict__ kh,
    const _Float16* __restrict__ vh, const float* __restrict__ gate,
    float* __restrict__ ctx)
{
    __shared__ __align__(16) char smem[32768];
    char* Kb = smem;            // 8KB  K tile
    char* Vb = smem + 8192;     // 8KB  V^T tile
    char* Pb = smem + 16384;    // 8KB  P, 2KB per wave

    const int tid = threadIdx.x;
    const int l = tid & 63;
    const int w = tid >> 6;
    // XCD grouping: each head's 16 blocks land on one XCD (round-robin model)
    const int wg = (blockIdx.x & 7) * 128 + (blockIdx.x >> 3);
    const int bh = wg >> 4;
    const int r0 = (wg & 15) * 64;

    const int lg = l >> 4;      // 0..3
    const int lm = l & 15;

    // Q A-fragments, hoisted: row = r0 + w*16 + lm, k(d) = 32*h + lg*8 + j
    const size_t qoff = ((size_t)bh * kS + r0 + w * 16 + lm) * kD + lg * 8;
    const half8 qf0 = *(const half8*)(qh + qoff);
    const half8 qf1 = *(const half8*)(qh + qoff + 32);

    const _Float16* kpt = kh + (size_t)bh * kS * kD;
    const _Float16* vpt = vh + (size_t)bh * kS * kD;

    float m_run[4], l_run[4];
    f32x4 acc_o[4];
#pragma unroll
    for (int r = 0; r < 4; ++r) {
        m_run[r] = -1e30f; l_run[r] = 0.f;
        acc_o[r] = (f32x4){0.f, 0.f, 0.f, 0.f};
    }

    for (int kt = 0; kt < 16; ++kt) {
        __syncthreads();
        // ---- stage K tile [kv][d] and V^T tile [d][kv] ----
#pragma unroll
        for (int p = 0; p < 2; ++p) {
            const int i = tid + p * 256;
            const int kv = i >> 3;            // 0..63
            const int d0 = (i & 7) * 8;
            const half8 kvec = *(const half8*)(kpt + (size_t)(kt * 64 + kv) * kD + d0);
            *(half8*)(Kb + swz(kv, d0 * 2)) = kvec;
            const half8 vvec = *(const half8*)(vpt + (size_t)(kt * 64 + kv) * kD + d0);
#pragma unroll
            for (int j = 0; j < 8; ++j)
                *(_Float16*)(Vb + swz(d0 + j, kv * 2)) = vvec[j];
        }
        __syncthreads();

        // ---- S = Q·K^T (16 q-rows x 64 kv) ----
        f32x4 s[4];
#pragma unroll
        for (int ct = 0; ct < 4; ++ct) {
            const int kvloc = ct * 16 + lm;
            const half8 b0 = *(const half8*)(Kb + swz(kvloc, lg * 16));
            const half8 b1 = *(const half8*)(Kb + swz(kvloc, 64 + lg * 16));
            f32x4 z = {0.f, 0.f, 0.f, 0.f};
            z = __builtin_amdgcn_mfma_f32_16x16x32_f16(qf0, b0, z, 0, 0, 0);
            z = __builtin_amdgcn_mfma_f32_16x16x32_f16(qf1, b1, z, 0, 0, 0);
            s[ct] = z;
        }

        // ---- online softmax; P -> wave-private LDS (f16) ----
        char* Pw = Pb + w * 2048;
#pragma unroll
        for (int r = 0; r < 4; ++r) {
            float mt = fmaxf(fmaxf(s[0][r], s[1][r]), fmaxf(s[2][r], s[3][r]));
#pragma unroll
            for (int off = 8; off > 0; off >>= 1) mt = fmaxf(mt, __shfl_xor(mt, off));
            const float mn = fmaxf(m_run[r], mt);
            const float corr = __expf(m_run[r] - mn);
            m_run[r] = mn;
            const float p0 = __expf(s[0][r] - mn);
            const float p1 = __expf(s[1][r] - mn);
            const float p2 = __expf(s[2][r] - mn);
            const float p3 = __expf(s[3][r] - mn);
            float ps = (p0 + p1) + (p2 + p3);
#pragma unroll
            for (int off = 8; off > 0; off >>= 1) ps += __shfl_xor(ps, off);
            l_run[r] = l_run[r] * corr + ps;
            const int qr = lg * 4 + r;
            *(_Float16*)(Pw + swz(qr, (0 * 16 + lm) * 2)) = (_Float16)p0;
            *(_Float16*)(Pw + swz(qr, (1 * 16 + lm) * 2)) = (_Float16)p1;
            *(_Float16*)(Pw + swz(qr, (2 * 16 + lm) * 2)) = (_Float16)p2;
            *(_Float16*)(Pw + swz(qr, (3 * 16 + lm) * 2)) = (_Float16)p3;
            acc_o[0][r] *= corr; acc_o[1][r] *= corr;
            acc_o[2][r] *= corr; acc_o[3][r] *= corr;
        }

        // ---- ctx += P·V  (wave-private P; no barrier needed) ----
        const half8 pa0 = *(const half8*)(Pw + swz(lm, lg * 16));
        const half8 pa1 = *(const half8*)(Pw + swz(lm, 64 + lg * 16));
#pragma unroll
        for (int dt = 0; dt < 4; ++dt) {
            const half8 vb0 = *(const half8*)(Vb + swz(dt * 16 + lm, lg * 16));
            const half8 vb1 = *(const half8*)(Vb + swz(dt * 16 + lm, 64 + lg * 16));
            acc_o[dt] = __builtin_amdgcn_mfma_f32_16x16x32_f16(pa0, vb0, acc_o[dt], 0, 0, 0);
            acc_o[dt] = __builtin_amdgcn_mfma_f32_16x16x32_f16(pa1, vb1, acc_o[dt], 0, 0, 0);
        }
    }

    // ---- epilogue: 1/l, gate, store ctx f32 ----
#pragma unroll
    for (int r = 0; r < 4; ++r) {
        const int row = r0 + w * 16 + lg * 4 + r;
        const float g = gate[bh * kS + row];
        const float f = g / l_run[r];
#pragma unroll
        for (int dt = 0; dt < 4; ++dt)
            ctx[((size_t)bh * kS + row) * kD + dt * 16 + lm] = acc_o[dt][r] * f;
    }
}

// ---------------------------------------------------------------------------
// Output projection (fp32): out[m,n] = sum_k ctx_perm[m,k]*proj_w[n,k] + b[n]
// ---------------------------------------------------------------------------
__global__ __launch_bounds__(256) void proj_kernel(
    const float* __restrict__ ctx, const float* __restrict__ w,
    const float* __restrict__ bias, float* __restrict__ out)
{
    __shared__ float As[16][132];
    __shared__ float Bs[16][132];
    const int tid = threadIdx.x;
    const int tx = tid & 15, ty = tid >> 4;
    const int n0 = blockIdx.x * 128, m0 = blockIdx.y * 128;
    const int b = m0 >> 10;

    float acc[8][8];
#pragma unroll
    for (int i = 0; i < 8; ++i)
#pragma unroll
        for (int j = 0; j < 8; ++j) acc[i][j] = 0.f;

    for (int k0 = 0; k0 < kC; k0 += 16) {
        __syncthreads();
#pragma unroll
        for (int l = 0; l < 2; ++l) {
            const int i = tid + l * 256;
            const int r = i >> 2, q4 = i & 3;
            const int np = (m0 + r) & 1023;
            const int k = k0 + q4 * 4;
            const int h = k >> 6, d = k & 63;
            const float4 av = *(const float4*)(ctx + ((size_t)(b * kH + h) * kS + np) * kD + d);
            const float4 bv = *(const float4*)(w + (n0 + r) * kC + k);
            As[q4 * 4 + 0][r] = av.x; As[q4 * 4 + 1][r] = av.y;
            As[q4 * 4 + 2][r] = av.z; As[q4 * 4 + 3][r] = av.w;
            Bs[q4 * 4 + 0][r] = bv.x; Bs[q4 * 4 + 1][r] = bv.y;
            Bs[q4 * 4 + 2][r] = bv.z; Bs[q4 * 4 + 3][r] = bv.w;
        }
        __syncthreads();
#pragma unroll
        for (int kk = 0; kk < 16; ++kk) {
            const float4 a0 = *(const float4*)&As[kk][ty * 4];
            const float4 a1 = *(const float4*)&As[kk][ty * 4 + 64];
            const float4 b0 = *(const float4*)&Bs[kk][tx * 4];
            const float4 b1 = *(const float4*)&Bs[kk][tx * 4 + 64];
            const float ar[8] = {a0.x, a0.y, a0.z, a0.w, a1.x, a1.y, a1.z, a1.w};
            const float br[8] = {b0.x, b0.y, b0.z, b0.w, b1.x, b1.y, b1.z, b1.w};
#pragma unroll
            for (int i = 0; i < 8; ++i)
#pragma unroll
                for (int j = 0; j < 8; ++j)
                    acc[i][j] = fmaf(ar[i], br[j], acc[i][j]);
        }
    }

    const int d0 = tx * 4;
    float blo[4], bhi[4];
#pragma unroll
    for (int j = 0; j < 4; ++j) {
        blo[j] = bias[n0 + d0 + j];
        bhi[j] = bias[n0 + 64 + d0 + j];
    }
#pragma unroll
    for (int i = 0; i < 8; ++i) {
        const int row = m0 + ty * 4 + (i < 4 ? i : 60 + i);
#pragma unroll
        for (int half = 0; half < 2; ++half) {
            float4 o;
            o.x = acc[i][half * 4 + 0] + (half ? bhi[0] : blo[0]);
            o.y = acc[i][half * 4 + 1] + (half ? bhi[1] : blo[1]);
            o.z = acc[i][half * 4 + 2] + (half ? bhi[2] : blo[2]);
            o.w = acc[i][half * 4 + 3] + (half ? bhi[3] : blo[3]);
            *(float4*)(out + row * kC + n0 + half * 64 + d0) = o;
        }
    }
}

// ---------------------------------------------------------------------------
extern "C" void kernel_launch(void* const* d_in, const int* in_sizes, int n_in,
                              void* d_out, int out_size, void* d_ws, size_t ws_size,
                              hipStream_t stream)
{
    const float* x      = (const float*)d_in[0];
    const float* qkv_w  = (const float*)d_in[1];
    const float* qkv_b  = (const float*)d_in[2];
    const float* qn_w   = (const float*)d_in[3];
    const float* qn_b   = (const float*)d_in[4];
    const float* kn_w   = (const float*)d_in[5];
    const float* kn_b   = (const float*)d_in[6];
    const float* gate_w = (const float*)d_in[7];
    const float* gate_b = (const float*)d_in[8];
    const float* proj_w = (const float*)d_in[9];
    const float* proj_b = (const float*)d_in[10];
    float* out = (float*)d_out;

    // workspace: qh | kh | vh (f16, 8MB each) | gate (256KB f32) | ctx (16MB f32)
    char* ws = (char*)d_ws;
    _Float16* qh  = (_Float16*)(ws);
    _Float16* khb = (_Float16*)(ws + (8u  << 20));
    _Float16* vhb = (_Float16*)(ws + (16u << 20));
    float*    gate = (float*)  (ws + (24u << 20));
    float*    ctx  = (float*)  (ws + (25u << 20));
    // total ws use: 41 MB

    qkv_kernel<<<dim3(12, 64), 256, 0, stream>>>(x, qkv_w, qkv_b, qn_w, qn_b,
                                                 kn_w, kn_b, qh, khb, vhb);
    gate_kernel<<<dim3(16384), 256, 0, stream>>>(x, gate_w, gate_b, gate);
    attn_kernel<<<dim3(1024), 256, 0, stream>>>(qh, khb, vhb, gate, ctx);
    proj_kernel<<<dim3(4, 64), 256, 0, stream>>>(ctx, proj_w, proj_b, out);
}

// Round 3
// 207.161 us; speedup vs baseline: 4.2449x; 1.8495x over previous
//
#include <hip/hip_runtime.h>
#include <math.h>

// Problem constants (B,N,C,H,D) = (8,1024,512,8,64)
constexpr int kB = 8, kS = 1024, kC = 512, kH = 8, kD = 64;

typedef _Float16 half8 __attribute__((ext_vector_type(8)));
typedef _Float16 half4v __attribute__((ext_vector_type(4)));
typedef float f32x4 __attribute__((ext_vector_type(4)));

typedef const __attribute__((address_space(1))) void* gas_t;
typedef __attribute__((address_space(3))) void* las_t;

// async global->LDS, 16B per lane; lds dest = wave base + lane*16 (linear)
__device__ __forceinline__ void gl_lds16(const _Float16* g, _Float16* l) {
    __builtin_amdgcn_global_load_lds((gas_t)g, (las_t)l, 16, 0, 0);
}

// ---------------------------------------------------------------------------
// Cast fp32 -> f16: x (4.19M), qkv_w (786K), proj_w (262K). Exact-grid, no tail.
// ---------------------------------------------------------------------------
__global__ __launch_bounds__(256) void cast_kernel(
    const float* __restrict__ x,  _Float16* __restrict__ xh,
    const float* __restrict__ w1, _Float16* __restrict__ w1h,
    const float* __restrict__ w2, _Float16* __restrict__ w2h)
{
    const int n0 = 4194304 / 4, n1 = 786432 / 4;
    const int idx = blockIdx.x * 256 + threadIdx.x;
    const float* s; _Float16* d; int off;
    if (idx < n0)           { s = x;  d = xh;  off = idx; }
    else if (idx < n0 + n1) { s = w1; d = w1h; off = idx - n0; }
    else                    { s = w2; d = w2h; off = idx - n0 - n1; }
    const float4 v = *(const float4*)(s + (size_t)off * 4);
    half4v o;
    o[0] = (_Float16)v.x; o[1] = (_Float16)v.y;
    o[2] = (_Float16)v.z; o[3] = (_Float16)v.w;
    *(half4v*)(d + (size_t)off * 4) = o;
}

// ---------------------------------------------------------------------------
// QKV GEMM, f16 MFMA: C[m,n] = sum_k xh[m,k]*wh[n,k] + bias[n]   (NT)
// M=8192 N=1536 K=512. 128x128 tile, BK=64, 4 waves x (4x4) 16x16x32 frags.
// Staging: global_load_lds 16B, source pre-swizzled (chunk ^= row&7), LDS
// dest linear; frag reads apply the same XOR -> granule-balanced b128.
// Epilogue: bias; q/k rows head-LayerNorm'd (D=64 == one wave-half, so the
// reduce is 4 in-reg cols + shfl_xor over 16 lanes); q scaled by D^-0.5;
// f16 scatter to q/k/v [bh][n][d].
// ---------------------------------------------------------------------------
__global__ __launch_bounds__(256) void qkv_kernel(
    const _Float16* __restrict__ xh, const _Float16* __restrict__ wh,
    const float* __restrict__ bias,
    const float* __restrict__ qn_w, const float* __restrict__ qn_b,
    const float* __restrict__ kn_w, const float* __restrict__ kn_b,
    _Float16* __restrict__ qb, _Float16* __restrict__ kb, _Float16* __restrict__ vb)
{
    __shared__ __align__(16) _Float16 smA[128 * 64];
    __shared__ __align__(16) _Float16 smB[128 * 64];
    const int tid = threadIdx.x;
    const int l = tid & 63, w = tid >> 6;
    const int lm = l & 15, lg = l >> 4;
    const int wr = w >> 1, wc = w & 1;
    const int n0 = blockIdx.x * 128, m0 = blockIdx.y * 128;

    // staging: dest chunk = p*256 + w*64 + lane; row = chunk>>3, c = chunk&7
    // LDS[row][c] <- global chunk (c ^ (row&7)) of that row
    const int src_c = (tid & 7) ^ ((tid >> 3) & 7);
    const int src_r = tid >> 3;                       // +32 per p
    const _Float16* aR = xh + (size_t)(m0 + src_r) * kC + src_c * 8;
    const _Float16* bR = wh + (size_t)(n0 + src_r) * kC + src_c * 8;

    f32x4 acc[4][4];
#pragma unroll
    for (int i = 0; i < 4; ++i)
#pragma unroll
        for (int j = 0; j < 4; ++j) acc[i][j] = (f32x4){0.f, 0.f, 0.f, 0.f};

    for (int kt = 0; kt < kC / 64; ++kt) {
        __syncthreads();
#pragma unroll
        for (int p = 0; p < 4; ++p) {
            gl_lds16(aR + (size_t)p * 32 * kC + kt * 64, smA + (p * 256 + w * 64) * 8);
            gl_lds16(bR + (size_t)p * 32 * kC + kt * 64, smB + (p * 256 + w * 64) * 8);
        }
        __syncthreads();   // drains vmcnt: tile resident
#pragma unroll
        for (int ks = 0; ks < 2; ++ks) {
            half8 a[4], b[4];
            const int cc = ((ks * 4 + lg) ^ (lm & 7)) * 8;
#pragma unroll
            for (int mi = 0; mi < 4; ++mi)
                a[mi] = *(const half8*)(smA + (wr * 64 + mi * 16 + lm) * 64 + cc);
#pragma unroll
            for (int ni = 0; ni < 4; ++ni)
                b[ni] = *(const half8*)(smB + (wc * 64 + ni * 16 + lm) * 64 + cc);
#pragma unroll
            for (int mi = 0; mi < 4; ++mi)
#pragma unroll
                for (int ni = 0; ni < 4; ++ni)
                    acc[mi][ni] = __builtin_amdgcn_mfma_f32_16x16x32_f16(
                        a[mi], b[ni], acc[mi][ni], 0, 0, 0);
        }
    }

    // ---- epilogue ----
    const int t = blockIdx.x >> 2;                 // 0:q 1:k 2:v
    const int h = ((blockIdx.x & 3) << 1) + wc;    // head (each wave = 1 head)
    _Float16* const outp = (t == 0) ? qb : (t == 1) ? kb : vb;
    const float osc = (t == 0) ? 0.125f : 1.0f;
    float bs[4], lw[4], lbv[4];
#pragma unroll
    for (int ni = 0; ni < 4; ++ni) {
        bs[ni] = bias[n0 + wc * 64 + ni * 16 + lm];
        lw[ni] = 1.f; lbv[ni] = 0.f;
    }
    if (t == 0) {
#pragma unroll
        for (int ni = 0; ni < 4; ++ni) { lw[ni] = qn_w[ni * 16 + lm]; lbv[ni] = qn_b[ni * 16 + lm]; }
    } else if (t == 1) {
#pragma unroll
        for (int ni = 0; ni < 4; ++ni) { lw[ni] = kn_w[ni * 16 + lm]; lbv[ni] = kn_b[ni * 16 + lm]; }
    }
#pragma unroll
    for (int mi = 0; mi < 4; ++mi) {
#pragma unroll
        for (int r = 0; r < 4; ++r) {
            float v[4];
#pragma unroll
            for (int ni = 0; ni < 4; ++ni) v[ni] = acc[mi][ni][r] + bs[ni];
            if (t < 2) {
                float s  = (v[0] + v[1]) + (v[2] + v[3]);
                float sq = (v[0] * v[0] + v[1] * v[1]) + (v[2] * v[2] + v[3] * v[3]);
#pragma unroll
                for (int off = 1; off < 16; off <<= 1) {
                    s  += __shfl_xor(s, off);
                    sq += __shfl_xor(sq, off);
                }
                const float mu  = s * (1.f / 64.f);
                const float var = sq * (1.f / 64.f) - mu * mu;
                const float rs  = rsqrtf(var + 1e-5f);
#pragma unroll
                for (int ni = 0; ni < 4; ++ni)
                    v[ni] = (v[ni] - mu) * rs * lw[ni] + lbv[ni];
            }
            const int token = m0 + wr * 64 + mi * 16 + lg * 4 + r;
            const int b = token >> 10, np = token & 1023;
            _Float16* dp = outp + ((size_t)(b * kH + h) * kS + np) * kD;
#pragma unroll
            for (int ni = 0; ni < 4; ++ni)
                dp[ni * 16 + lm] = (_Float16)(v[ni] * osc);
        }
    }
}

// ---------------------------------------------------------------------------
// Gate: gate[bh][n] = sigmoid(dot(x[b,n,h*64:], gate_w[h]) + gate_b[h]) (fp32)
// ---------------------------------------------------------------------------
__global__ __launch_bounds__(256) void gate_kernel(
    const float* __restrict__ x, const float* __restrict__ gw,
    const float* __restrict__ gb, float* __restrict__ gate)
{
    const int wid  = (blockIdx.x * 256 + threadIdx.x) >> 6;
    const int lane = threadIdx.x & 63;
    const int bh = wid >> 10, n = wid & 1023;
    const int b = bh >> 3, h = bh & 7;
    float a = x[(b * kS + n) * kC + h * kD + lane] * gw[h * kD + lane];
#pragma unroll
    for (int off = 32; off > 0; off >>= 1) a += __shfl_xor(a, off);
    if (lane == 0) {
        const float al = a + gb[h];
        gate[bh * kS + n] = 1.0f / (1.0f + __expf(-al));
    }
}

// ---------------------------------------------------------------------------
// Flash attention, f16 MFMA (unchanged structure from round 2; ctx now f16
// in [b][n][h*64+d] layout so proj can stage it directly; setprio on MFMAs).
// ---------------------------------------------------------------------------
__device__ __forceinline__ int swz(int row, int inner) {
    return row * 128 + (inner ^ ((((row >> 3) ^ row) & 7) << 4));
}

__global__ __launch_bounds__(256) void attn_kernel(
    const _Float16* __restrict__ qh, const _Float16* __restrict__ kh,
    const _Float16* __restrict__ vh, const float* __restrict__ gate,
    _Float16* __restrict__ ctx)
{
    __shared__ __align__(16) char smem[32768];
    char* Kb = smem;            // 8KB  K tile
    char* Vb = smem + 8192;     // 8KB  V^T tile
    char* Pb = smem + 16384;    // 8KB  P, 2KB per wave

    const int tid = threadIdx.x;
    const int l = tid & 63;
    const int w = tid >> 6;
    const int wg = (blockIdx.x & 7) * 128 + (blockIdx.x >> 3);
    const int bh = wg >> 4;
    const int r0 = (wg & 15) * 64;

    const int lg = l >> 4;
    const int lm = l & 15;

    const size_t qoff = ((size_t)bh * kS + r0 + w * 16 + lm) * kD + lg * 8;
    const half8 qf0 = *(const half8*)(qh + qoff);
    const half8 qf1 = *(const half8*)(qh + qoff + 32);

    const _Float16* kpt = kh + (size_t)bh * kS * kD;
    const _Float16* vpt = vh + (size_t)bh * kS * kD;

    float m_run[4], l_run[4];
    f32x4 acc_o[4];
#pragma unroll
    for (int r = 0; r < 4; ++r) {
        m_run[r] = -1e30f; l_run[r] = 0.f;
        acc_o[r] = (f32x4){0.f, 0.f, 0.f, 0.f};
    }

    for (int kt = 0; kt < 16; ++kt) {
        __syncthreads();
#pragma unroll
        for (int p = 0; p < 2; ++p) {
            const int i = tid + p * 256;
            const int kv = i >> 3;
            const int d0 = (i & 7) * 8;
            const half8 kvec = *(const half8*)(kpt + (size_t)(kt * 64 + kv) * kD + d0);
            *(half8*)(Kb + swz(kv, d0 * 2)) = kvec;
            const half8 vvec = *(const half8*)(vpt + (size_t)(kt * 64 + kv) * kD + d0);
#pragma unroll
            for (int j = 0; j < 8; ++j)
                *(_Float16*)(Vb + swz(d0 + j, kv * 2)) = vvec[j];
        }
        __syncthreads();

        // ---- S = Q.K^T ----
        f32x4 s[4];
        __builtin_amdgcn_s_setprio(1);
#pragma unroll
        for (int ct = 0; ct < 4; ++ct) {
            const int kvloc = ct * 16 + lm;
            const half8 b0 = *(const half8*)(Kb + swz(kvloc, lg * 16));
            const half8 b1 = *(const half8*)(Kb + swz(kvloc, 64 + lg * 16));
            f32x4 z = {0.f, 0.f, 0.f, 0.f};
            z = __builtin_amdgcn_mfma_f32_16x16x32_f16(qf0, b0, z, 0, 0, 0);
            z = __builtin_amdgcn_mfma_f32_16x16x32_f16(qf1, b1, z, 0, 0, 0);
            s[ct] = z;
        }
        __builtin_amdgcn_s_setprio(0);

        // ---- online softmax; P -> wave-private LDS (f16) ----
        char* Pw = Pb + w * 2048;
#pragma unroll
        for (int r = 0; r < 4; ++r) {
            float mt = fmaxf(fmaxf(s[0][r], s[1][r]), fmaxf(s[2][r], s[3][r]));
#pragma unroll
            for (int off = 8; off > 0; off >>= 1) mt = fmaxf(mt, __shfl_xor(mt, off));
            const float mn = fmaxf(m_run[r], mt);
            const float corr = __expf(m_run[r] - mn);
            m_run[r] = mn;
            const float p0 = __expf(s[0][r] - mn);
            const float p1 = __expf(s[1][r] - mn);
            const float p2 = __expf(s[2][r] - mn);
            const float p3 = __expf(s[3][r] - mn);
            float ps = (p0 + p1) + (p2 + p3);
#pragma unroll
            for (int off = 8; off > 0; off >>= 1) ps += __shfl_xor(ps, off);
            l_run[r] = l_run[r] * corr + ps;
            const int qr = lg * 4 + r;
            *(_Float16*)(Pw + swz(qr, (0 * 16 + lm) * 2)) = (_Float16)p0;
            *(_Float16*)(Pw + swz(qr, (1 * 16 + lm) * 2)) = (_Float16)p1;
            *(_Float16*)(Pw + swz(qr, (2 * 16 + lm) * 2)) = (_Float16)p2;
            *(_Float16*)(Pw + swz(qr, (3 * 16 + lm) * 2)) = (_Float16)p3;
            acc_o[0][r] *= corr; acc_o[1][r] *= corr;
            acc_o[2][r] *= corr; acc_o[3][r] *= corr;
        }

        // ---- ctx += P.V ----
        const half8 pa0 = *(const half8*)(Pw + swz(lm, lg * 16));
        const half8 pa1 = *(const half8*)(Pw + swz(lm, 64 + lg * 16));
        __builtin_amdgcn_s_setprio(1);
#pragma unroll
        for (int dt = 0; dt < 4; ++dt) {
            const half8 vb0 = *(const half8*)(Vb + swz(dt * 16 + lm, lg * 16));
            const half8 vb1 = *(const half8*)(Vb + swz(dt * 16 + lm, 64 + lg * 16));
            acc_o[dt] = __builtin_amdgcn_mfma_f32_16x16x32_f16(pa0, vb0, acc_o[dt], 0, 0, 0);
            acc_o[dt] = __builtin_amdgcn_mfma_f32_16x16x32_f16(pa1, vb1, acc_o[dt], 0, 0, 0);
        }
        __builtin_amdgcn_s_setprio(0);
    }

    // ---- epilogue: 1/l, gate, store ctx f16 at [b][n][h*64+d] ----
    const int b = bh >> 3, hh = bh & 7;
#pragma unroll
    for (int r = 0; r < 4; ++r) {
        const int row = r0 + w * 16 + lg * 4 + r;
        const float g = gate[bh * kS + row];
        const float f = g / l_run[r];
        _Float16* dp = ctx + ((size_t)(b * kS + row)) * kC + hh * kD;
#pragma unroll
        for (int dt = 0; dt < 4; ++dt)
            dp[dt * 16 + lm] = (_Float16)(acc_o[dt][r] * f);
    }
}

// ---------------------------------------------------------------------------
// Output projection, f16 MFMA: out[m,n] = sum_k ctx[m,k]*proj_w[n,k] + b[n]
// M=8192 N=512 K=512. Same structure as qkv_kernel; fp32 output.
// ---------------------------------------------------------------------------
__global__ __launch_bounds__(256) void proj_kernel(
    const _Float16* __restrict__ ah, const _Float16* __restrict__ wh,
    const float* __restrict__ bias, float* __restrict__ out)
{
    __shared__ __align__(16) _Float16 smA[128 * 64];
    __shared__ __align__(16) _Float16 smB[128 * 64];
    const int tid = threadIdx.x;
    const int l = tid & 63, w = tid >> 6;
    const int lm = l & 15, lg = l >> 4;
    const int wr = w >> 1, wc = w & 1;
    const int n0 = blockIdx.x * 128, m0 = blockIdx.y * 128;

    const int src_c = (tid & 7) ^ ((tid >> 3) & 7);
    const int src_r = tid >> 3;
    const _Float16* aR = ah + (size_t)(m0 + src_r) * kC + src_c * 8;
    const _Float16* bR = wh + (size_t)(n0 + src_r) * kC + src_c * 8;

    f32x4 acc[4][4];
#pragma unroll
    for (int i = 0; i < 4; ++i)
#pragma unroll
        for (int j = 0; j < 4; ++j) acc[i][j] = (f32x4){0.f, 0.f, 0.f, 0.f};

    for (int kt = 0; kt < kC / 64; ++kt) {
        __syncthreads();
#pragma unroll
        for (int p = 0; p < 4; ++p) {
            gl_lds16(aR + (size_t)p * 32 * kC + kt * 64, smA + (p * 256 + w * 64) * 8);
            gl_lds16(bR + (size_t)p * 32 * kC + kt * 64, smB + (p * 256 + w * 64) * 8);
        }
        __syncthreads();
#pragma unroll
        for (int ks = 0; ks < 2; ++ks) {
            half8 a[4], b[4];
            const int cc = ((ks * 4 + lg) ^ (lm & 7)) * 8;
#pragma unroll
            for (int mi = 0; mi < 4; ++mi)
                a[mi] = *(const half8*)(smA + (wr * 64 + mi * 16 + lm) * 64 + cc);
#pragma unroll
            for (int ni = 0; ni < 4; ++ni)
                b[ni] = *(const half8*)(smB + (wc * 64 + ni * 16 + lm) * 64 + cc);
#pragma unroll
            for (int mi = 0; mi < 4; ++mi)
#pragma unroll
                for (int ni = 0; ni < 4; ++ni)
                    acc[mi][ni] = __builtin_amdgcn_mfma_f32_16x16x32_f16(
                        a[mi], b[ni], acc[mi][ni], 0, 0, 0);
        }
    }

    float bs[4];
#pragma unroll
    for (int ni = 0; ni < 4; ++ni) bs[ni] = bias[n0 + wc * 64 + ni * 16 + lm];
#pragma unroll
    for (int mi = 0; mi < 4; ++mi) {
#pragma unroll
        for (int r = 0; r < 4; ++r) {
            const int token = m0 + wr * 64 + mi * 16 + lg * 4 + r;
            float* dp = out + (size_t)token * kC + n0 + wc * 64 + lm;
#pragma unroll
            for (int ni = 0; ni < 4; ++ni)
                dp[ni * 16] = acc[mi][ni][r] + bs[ni];
        }
    }
}

// ---------------------------------------------------------------------------
extern "C" void kernel_launch(void* const* d_in, const int* in_sizes, int n_in,
                              void* d_out, int out_size, void* d_ws, size_t ws_size,
                              hipStream_t stream)
{
    const float* x      = (const float*)d_in[0];
    const float* qkv_w  = (const float*)d_in[1];
    const float* qkv_b  = (const float*)d_in[2];
    const float* qn_w   = (const float*)d_in[3];
    const float* qn_b   = (const float*)d_in[4];
    const float* kn_w   = (const float*)d_in[5];
    const float* kn_b   = (const float*)d_in[6];
    const float* gate_w = (const float*)d_in[7];
    const float* gate_b = (const float*)d_in[8];
    const float* proj_w = (const float*)d_in[9];
    const float* proj_b = (const float*)d_in[10];
    float* out = (float*)d_out;

    // workspace layout (bytes)
    char* ws = (char*)d_ws;
    _Float16* xh    = (_Float16*)(ws);                 //  8,388,608
    _Float16* wqkvh = (_Float16*)(ws + 8388608);       //  1,572,864
    _Float16* wprjh = (_Float16*)(ws + 9961472);       //    524,288
    _Float16* qh    = (_Float16*)(ws + 10485760);      //  8,388,608
    _Float16* khb   = (_Float16*)(ws + 18874368);      //  8,388,608
    _Float16* vhb   = (_Float16*)(ws + 27262976);      //  8,388,608
    _Float16* ctxh  = (_Float16*)(ws + 35651584);      //  8,388,608
    float*    gate  = (float*)   (ws + 44040192);      //    262,144
    // total 44.3 MB

    cast_kernel<<<dim3(5120), 256, 0, stream>>>(x, xh, qkv_w, wqkvh, proj_w, wprjh);
    qkv_kernel<<<dim3(12, 64), 256, 0, stream>>>(xh, wqkvh, qkv_b, qn_w, qn_b,
                                                 kn_w, kn_b, qh, khb, vhb);
    gate_kernel<<<dim3(16384), 256, 0, stream>>>(x, gate_w, gate_b, gate);
    attn_kernel<<<dim3(1024), 256, 0, stream>>>(qh, khb, vhb, gate, ctxh);
    proj_kernel<<<dim3(4, 64), 256, 0, stream>>>(ctxh, proj_w == nullptr ? wprjh : wprjh,
                                                 proj_b, out);
}